// Round 1
// baseline (3058.995 us; speedup 1.0000x reference)
//
#include <hip/hip_runtime.h>
#include <cmath>

#define S_CNT 50
#define T_CNT 2048
#define I_DIM 64
#define H_DIM 256
#define CH    32          // timestep staging chunk
#define NTHR  512

__device__ __forceinline__ float fast_tanh(float x) {
    float e = __expf(2.0f * x);
    return 1.0f - __fdividef(2.0f, e + 1.0f);
}

// Layout: tid = jg*16 + p;  jg in [0,32) owns output rows j = jg*8 + r (r<8);
// p in [0,16) owns g-slice [p*16, p*16+16) of W_hh and i-slice [p*4, p*4+4) of W_ih.
__launch_bounds__(NTHR, 2)
__global__ void rnn_fused_kernel(const float* __restrict__ input_data, // S,T,65
                                 const float* __restrict__ hidden,     // S,H
                                 const float* __restrict__ fe,         // S,T
                                 const float* __restrict__ W_ih,       // S,H,I
                                 const float* __restrict__ W_hh,       // S,H,H
                                 const float* __restrict__ b_ih,       // S,H
                                 const float* __restrict__ b_hh,       // S,H
                                 const float* __restrict__ W_lin,      // S,1,H
                                 const float* __restrict__ b_lin,      // S,1
                                 float* __restrict__ out)              // 1 + S*T
{
    const int s    = blockIdx.x;
    const int tid  = threadIdx.x;
    const int jg   = tid >> 4;     // 0..31
    const int p    = tid & 15;     // 0..15
    const int lane = tid & 63;
    const int wv   = tid >> 6;     // wave id 0..7

    __shared__ float hbuf[2][H_DIM];
    __shared__ float xbuf[CH][I_DIM];
    __shared__ float zbuf[2][CH];
    __shared__ float febuf[2][CH];
    __shared__ float wavesum[2][8];
    __shared__ float bias_lds[H_DIM];
    __shared__ float wlin_lds[H_DIM];

    // ---- init ----
    for (int j = tid; j < H_DIM; j += NTHR) {
        hbuf[1][j]   = hidden[s * H_DIM + j];
        bias_lds[j]  = b_ih[s * H_DIM + j] + b_hh[s * H_DIM + j];
        wlin_lds[j]  = W_lin[s * H_DIM + j];
    }

    // weights into registers
    float4 w4[8][4];   // W_hh[j = jg*8+r][p*16 + q*4 + 0..3]
    float4 wx4[8];     // W_ih[j][p*4 + 0..3]
    const float* whh_base = W_hh + (size_t)s * H_DIM * H_DIM;
    const float* wih_base = W_ih + (size_t)s * H_DIM * I_DIM;
#pragma unroll
    for (int r = 0; r < 8; ++r) {
        const int j = jg * 8 + r;
        const float4* rowp =
            reinterpret_cast<const float4*>(whh_base + (size_t)j * H_DIM + p * 16);
#pragma unroll
        for (int q = 0; q < 4; ++q) w4[r][q] = rowp[q];
        wx4[r] = *reinterpret_cast<const float4*>(wih_base + (size_t)j * I_DIM + p * 4);
    }

    const float blin = b_lin[s];
    float ll = 0.f;
    float* sig_out       = out + 1 + (size_t)s * T_CNT;
    const float* in_base = input_data + (size_t)s * T_CNT * 65;
    const float* fe_base = fe + (size_t)s * T_CNT;

    __syncthreads();

    for (int c = 0; c < T_CNT / CH; ++c) {
        const int t0    = c * CH;
        const int par_c = c & 1;
        // ---- stage a chunk of inputs ----
        for (int idx = tid; idx < CH * 65; idx += NTHR) {
            const int row = idx / 65;
            const int col = idx - row * 65;
            const float v = in_base[(size_t)(t0 + row) * 65 + col];
            if (col == 0) zbuf[par_c][row] = v;
            else          xbuf[row][col - 1] = v;
        }
        if (tid < CH) febuf[par_c][tid] = fe_base[t0 + tid];
        __syncthreads();

        for (int tt = 0; tt < CH; ++tt) {
            const int t = t0 + tt;

            // thread 0 finalizes sigma / log-lik for step t-1 (deferred)
            if (tid == 0 && t > 0) {
                const int tm = t - 1;
                const int pm = tm & 1;
                float sg = wavesum[pm][0] + wavesum[pm][1] + wavesum[pm][2] + wavesum[pm][3]
                         + wavesum[pm][4] + wavesum[pm][5] + wavesum[pm][6] + wavesum[pm][7]
                         + blin;
                const float sigma = fabsf(sg);
                sig_out[tm] = sigma;
                const int cm = (tm >> 5) & 1;   // chunk parity of tm
                const int rm = tm & (CH - 1);
                const float diff = zbuf[cm][rm] - febuf[cm][rm];
                ll += -(diff * diff) / (2.f * sigma * sigma);
            }

            const int rp = (t + 1) & 1;   // read parity for h

            float acc[8];
#pragma unroll
            for (int r = 0; r < 8; ++r) acc[r] = 0.f;

            // W_ih part
            {
                const float4 xv = *reinterpret_cast<const float4*>(&xbuf[tt][p * 4]);
#pragma unroll
                for (int r = 0; r < 8; ++r) {
                    acc[r] = fmaf(wx4[r].x, xv.x, acc[r]);
                    acc[r] = fmaf(wx4[r].y, xv.y, acc[r]);
                    acc[r] = fmaf(wx4[r].z, xv.z, acc[r]);
                    acc[r] = fmaf(wx4[r].w, xv.w, acc[r]);
                }
            }
            // W_hh part
#pragma unroll
            for (int q = 0; q < 4; ++q) {
                const float4 hv =
                    *reinterpret_cast<const float4*>(&hbuf[rp][p * 16 + q * 4]);
#pragma unroll
                for (int r = 0; r < 8; ++r) {
                    acc[r] = fmaf(w4[r][q].x, hv.x, acc[r]);
                    acc[r] = fmaf(w4[r][q].y, hv.y, acc[r]);
                    acc[r] = fmaf(w4[r][q].z, hv.z, acc[r]);
                    acc[r] = fmaf(w4[r][q].w, hv.w, acc[r]);
                }
            }

            // butterfly reduce over the 16-lane g-split
#pragma unroll
            for (int m = 1; m <= 8; m <<= 1) {
#pragma unroll
                for (int r = 0; r < 8; ++r) acc[r] += __shfl_xor(acc[r], m, 64);
            }

            // select acc[p&7] without dynamic register indexing
            const int b0 = p & 1, b1 = p & 2, b2 = p & 4;
            float s0 = b0 ? acc[1] : acc[0];
            float s1 = b0 ? acc[3] : acc[2];
            float s2 = b0 ? acc[5] : acc[4];
            float s3 = b0 ? acc[7] : acc[6];
            float u0 = b1 ? s1 : s0;
            float u1 = b1 ? s3 : s2;
            float v  = b2 ? u1 : u0;

            const int j = jg * 8 + (p & 7);
            const float a = v + bias_lds[j];
            const float h = fast_tanh(a);
            if (p < 8) hbuf[t & 1][j] = h;

            float sv = (p < 8) ? h * wlin_lds[j] : 0.f;
#pragma unroll
            for (int m = 1; m <= 32; m <<= 1) sv += __shfl_xor(sv, m, 64);
            if (lane == 0) wavesum[t & 1][wv] = sv;

            __syncthreads();
        }
    }

    // finalize last step + commit log-lik
    if (tid == 0) {
        const int tm = T_CNT - 1;
        const int pm = tm & 1;
        float sg = wavesum[pm][0] + wavesum[pm][1] + wavesum[pm][2] + wavesum[pm][3]
                 + wavesum[pm][4] + wavesum[pm][5] + wavesum[pm][6] + wavesum[pm][7]
                 + blin;
        const float sigma = fabsf(sg);
        sig_out[tm] = sigma;
        const int cm = (tm >> 5) & 1;
        const int rm = tm & (CH - 1);
        const float diff = zbuf[cm][rm] - febuf[cm][rm];
        ll += -(diff * diff) / (2.f * sigma * sigma);
        atomicAdd(out, ll);
    }
}

extern "C" void kernel_launch(void* const* d_in, const int* in_sizes, int n_in,
                              void* d_out, int out_size, void* d_ws, size_t ws_size,
                              hipStream_t stream) {
    (void)in_sizes; (void)n_in; (void)d_ws; (void)ws_size; (void)out_size;
    const float* input_data = (const float*)d_in[0];
    const float* hidden     = (const float*)d_in[1];
    const float* fe         = (const float*)d_in[2];
    const float* W_ih       = (const float*)d_in[3];
    const float* W_hh       = (const float*)d_in[4];
    const float* b_ih       = (const float*)d_in[5];
    const float* b_hh       = (const float*)d_in[6];
    const float* W_lin      = (const float*)d_in[7];
    const float* b_lin      = (const float*)d_in[8];
    float* out = (float*)d_out;

    hipMemsetAsync(d_out, 0, sizeof(float), stream);
    rnn_fused_kernel<<<dim3(S_CNT), dim3(NTHR), 0, stream>>>(
        input_data, hidden, fe, W_ih, W_hh, b_ih, b_hh, W_lin, b_lin, out);
}